// Round 3
// baseline (121.460 us; speedup 1.0000x reference)
//
#include <hip/hip_runtime.h>
#include <hip/hip_bf16.h>

#define EPSW 1e-6f

typedef __attribute__((ext_vector_type(4))) float floatx4;
typedef __attribute__((ext_vector_type(4))) unsigned int uintx4;
typedef __attribute__((ext_vector_type(8))) short shortx8;   // 8 bf16 (4 VGPRs)

// round-to-nearest-even float -> bf16 bits (finite inputs)
__device__ __forceinline__ unsigned short f2bf(float f) {
    unsigned int u = __float_as_uint(f);
    u = (u + 0x7fffu + ((u >> 16) & 1u)) >> 16;
    return (unsigned short)u;
}

__device__ __forceinline__ float bf2f(unsigned short b) {
    return __uint_as_float((unsigned int)b << 16);
}

__device__ __forceinline__ unsigned int pk2(float lo, float hi) {
    return (unsigned int)f2bf(lo) | ((unsigned int)f2bf(hi) << 16);
}

// async global->LDS DMA, 16B per lane: lane i's 16B land at l + i*16.
__device__ __forceinline__ void gl_lds16(const void* g, void* l) {
    __builtin_amdgcn_global_load_lds(
        (const __attribute__((address_space(1))) unsigned int*)g,
        (__attribute__((address_space(3))) unsigned int*)l, 16, 0, 0);
}

// ---------------------------------------------------------------------------
// prep: 20 blocks x 512 threads.
//   blocks 0..15 : W -> wt bf16, granule (kg,h) at kg*128+h, zero-padded.
//                  block 0 also zeroes the per-batch completion counters.
//   blocks 16..19: Mt[c][n] = (A@A)[n][c], n-sliced 16 rows per block.
// (bias prefill REMOVED -- finisher writes y = bias + M@z with plain stores.)
// ---------------------------------------------------------------------------
__global__ __launch_bounds__(512) void prep(const float* __restrict__ W,
                                            const int* __restrict__ ei,
                                            const float* __restrict__ ew,
                                            unsigned short* __restrict__ wt,
                                            float* __restrict__ Mt,
                                            int* __restrict__ cnt) {
    __shared__ float sA[4096 + 128];
    const int bid = blockIdx.x;
    const int t   = threadIdx.x;

    if (bid < 16) {
        if (bid == 0 && t < 32) cnt[t] = 0;   // reset last-done counters
#pragma unroll
        for (int i = 0; i < 4; ++i) {
            const int G  = bid * 2048 + i * 512 + t;  // 0..32767
            const int kg = G >> 7;
            const int h  = G & 127;
            const int k  = kg * 8;
            floatx4 v0 = (floatx4){0.f, 0.f, 0.f, 0.f};
            floatx4 v1 = (floatx4){0.f, 0.f, 0.f, 0.f};
            if (k < 2000) {  // kg<=249 -> whole granule valid
                v0 = *(const floatx4*)(W + (size_t)h * 2000 + k);
                v1 = *(const floatx4*)(W + (size_t)h * 2000 + k + 4);
            }
            unsigned short* p = wt + ((size_t)kg * 128 + h) * 8;
            p[0] = f2bf(v0.x); p[1] = f2bf(v0.y); p[2] = f2bf(v0.z); p[3] = f2bf(v0.w);
            p[4] = f2bf(v1.x); p[5] = f2bf(v1.y); p[6] = f2bf(v1.z); p[7] = f2bf(v1.w);
        }
    } else {
        const int bb = bid - 16;                // 0..3: n-slice [bb*16, bb*16+16)
        float* A    = sA;                       // 4096 f, A[n][k] (row-major)
        float* deg  = sA + 4096;
        float* dinv = deg + 64;
        if (t < 64) deg[t] = 1.0f;              // self-loop pre-added
        for (int i = t; i < 4096; i += 512) A[i] = 0.0f;
        __syncthreads();
        const int* srcp = ei;
        const int* dstp = ei + 4096;
#pragma unroll
        for (int i = 0; i < 8; ++i) {
            const int e = i * 512 + t;
            float w = ew[e];
            w = (w <= 0.0f) ? EPSW : w;
            atomicAdd(&deg[dstp[e]], w);
        }
        __syncthreads();
        if (t < 64) dinv[t] = 1.0f / sqrtf(deg[t]);
        __syncthreads();
#pragma unroll
        for (int i = 0; i < 8; ++i) {
            const int e = i * 512 + t;
            float w = ew[e];
            w = (w <= 0.0f) ? EPSW : w;
            const int s = srcp[e], d = dstp[e];
            atomicAdd(&A[d * 64 + s], dinv[s] * w * dinv[d]);
        }
        if (t < 64) atomicAdd(&A[t * 64 + t], dinv[t] * dinv[t]);
        __syncthreads();
        const int c  = t & 63;
        const int n0 = bb * 16 + (t >> 6);
        const int n1 = n0 + 8;
        float s0 = 0.0f, s1 = 0.0f;
#pragma unroll 8
        for (int k = 0; k < 64; ++k) {
            const float akc = A[k * 64 + c];
            s0 += A[n0 * 64 + k] * akc;
            s1 += A[n1 * 64 + k] * akc;
        }
        Mt[c * 64 + n0] = s0;
        Mt[c * 64 + n1] = s1;
    }
}

// ---------------------------------------------------------------------------
// gemm_fused: 256 blocks x 256 threads (4 waves).
// bid mapping (XCD-clustering heuristic -- speed only, not correctness):
//   bb = (bid&7) | ((bid>>6)<<3)  (batch 0..31), ks = (bid>>3)&7.
// All 8 ks-blocks of a batch share bid%8, i.e. (likely) one XCD -> zp
// partials stay in that XCD's L2 for the finisher.
// Main loop == r1's proven gemm_lds (fused x fp32->bf16 A-staging, gl_lds16
// B-staging from wt, double-buffered, 4 chunks of BK=64, 16 MFMA/chunk).
// Combine (NEW): each block stores its fp32 partial to a PRIVATE zp slice
// (plain stores), __threadfence + per-batch counter; the 8th (last-done)
// block re-reads the 8 slices, sums, applies M via error-split bf16 MFMA
// (Mhi*zhi + Mhi*zlo + Mlo*zhi), and writes y = bias + M@z with plain
// stores. No global atomic storms, no third kernel, no grid-wide barrier.
// ---------------------------------------------------------------------------
__global__ __launch_bounds__(256) void gemm_fused(
        const float* __restrict__ x,
        const unsigned short* __restrict__ wt,
        const float* __restrict__ Mtg,
        const float* __restrict__ bias,
        float* __restrict__ zp,
        int* __restrict__ cnt,
        float* __restrict__ y) {
    __shared__ __align__(16) unsigned char smem[2][24576];
    __shared__ __align__(16) unsigned char mg[16384];   // Mhi | Mlo granules
    __shared__ int lastS;
    const int t    = threadIdx.x;
    const int wave = t >> 6, lane = t & 63;
    const int m = lane & 15, q = lane >> 4;
    const int bid   = blockIdx.x;
    const int bb    = (bid & 7) | ((bid >> 6) << 3);  // batch 0..31
    const int ks    = (bid >> 3) & 7;                 // K-slice 0..7
    const int rbase = bb * 64;
    const int kg0   = ks * 32;

    const int kgl = lane >> 3;               // 0..7  A-staging granule col
    const int rr0 = wave * 8 + (lane & 7);   // A-staging row (i=0); +32 for i=1

    floatx4 acc[4][2];
#pragma unroll
    for (int rt = 0; rt < 4; ++rt)
#pragma unroll
        for (int hh = 0; hh < 2; ++hh)
            acc[rt][hh] = (floatx4){0.f, 0.f, 0.f, 0.f};

    floatx4 va0, va1, vb0, vb1;  // staged x: rows rr0 / rr0+32, 8 k each

#define LOAD_A(c)                                                             \
    {                                                                         \
        const int k_ = ks * 256 + (c) * 64 + kgl * 8;                         \
        const float* px_ = x + (size_t)(rbase + rr0) * 2000 + k_;             \
        if (k_ < 2000) {                                                      \
            va0 = *(const floatx4*)px_;                                       \
            va1 = *(const floatx4*)(px_ + 4);                                 \
            vb0 = *(const floatx4*)(px_ + 64000);                             \
            vb1 = *(const floatx4*)(px_ + 64004);                             \
        } else {                                                              \
            va0 = va1 = vb0 = vb1 = (floatx4){0.f, 0.f, 0.f, 0.f};            \
        }                                                                     \
    }

#define WRITE_A(c)                                                            \
    {                                                                         \
        unsigned char* sb_ = smem[(c) & 1];                                   \
        uintx4 g0_, g1_;                                                      \
        g0_.x = pk2(va0.x, va0.y); g0_.y = pk2(va0.z, va0.w);                 \
        g0_.z = pk2(va1.x, va1.y); g0_.w = pk2(va1.z, va1.w);                 \
        g1_.x = pk2(vb0.x, vb0.y); g1_.y = pk2(vb0.z, vb0.w);                 \
        g1_.z = pk2(vb1.x, vb1.y); g1_.w = pk2(vb1.z, vb1.w);                 \
        *(uintx4*)(sb_ + kgl * 1024 + rr0 * 16) = g0_;                        \
        *(uintx4*)(sb_ + kgl * 1024 + (rr0 + 32) * 16) = g1_;                 \
    }

#define ISSUE_B(c)                                                            \
    {                                                                         \
        unsigned char* sb_ = smem[(c) & 1];                                   \
        const int ckg_ = kg0 + (c) * 8;                                       \
        for (int j = wave; j < 16; j += 4) {                                  \
            const int kb_ = j >> 1, hf_ = j & 1;                              \
            gl_lds16(wt + ((size_t)(ckg_ + kb_) * 128 + hf_ * 64 + lane) * 8, \
                     sb_ + 8192 + kb_ * 2048 + hf_ * 1024);                   \
        }                                                                     \
    }

    LOAD_A(0);
    ISSUE_B(0);
    for (int c = 0; c < 4; ++c) {
        __builtin_amdgcn_s_waitcnt(0);   // own A regs + B DMA drained
        WRITE_A(c);                      // bf16 granules into buf c&1
        if (c < 3) {                     // overlap next chunk's HBM latency
            LOAD_A(c + 1);
            ISSUE_B(c + 1);
        }
        __syncthreads();                 // all waves' A writes + B DMA published
        const unsigned char* sb = smem[c & 1];
#pragma unroll
        for (int p = 0; p < 2; ++p) {
            shortx8 a[4];
#pragma unroll
            for (int rt = 0; rt < 4; ++rt)
                a[rt] = *(const shortx8*)(sb + (p * 4 + q) * 1024 + (rt * 16 + m) * 16);
            shortx8 bbf[2];
#pragma unroll
            for (int hh = 0; hh < 2; ++hh)
                bbf[hh] = *(const shortx8*)(sb + 8192 + (p * 4 + q) * 2048 +
                                            ((wave + hh * 4) * 16 + m) * 16);
#pragma unroll
            for (int rt = 0; rt < 4; ++rt)
#pragma unroll
                for (int hh = 0; hh < 2; ++hh)
                    acc[rt][hh] = __builtin_amdgcn_mfma_f32_16x16x32_bf16(
                        a[rt], bbf[hh], acc[rt][hh], 0, 0, 0);
        }
        __syncthreads();                 // all reads of buf c done before reuse
    }
#undef LOAD_A
#undef WRITE_A
#undef ISSUE_B

    // ---- store private fp32 partial: zp[bb][ks][n][h] ---------------------
    // C/D layout: row n = rt*16 + q*4 + v, col h = (wave+hh*4)*16 + m.
    float* zslice = zp + ((size_t)bb * 8 + ks) * 8192;
#pragma unroll
    for (int rt = 0; rt < 4; ++rt)
#pragma unroll
        for (int hh = 0; hh < 2; ++hh) {
            const int h = (wave + hh * 4) * 16 + m;
#pragma unroll
            for (int v = 0; v < 4; ++v) {
                const int n = rt * 16 + q * 4 + v;
                zslice[n * 128 + h] = acc[rt][hh][v];
            }
        }

    // ---- last-done detection (release: fence + device-scope atomic) -------
    __threadfence();                     // my stores visible at device scope
    __syncthreads();                     // all threads' stores covered
    if (t == 0) lastS = (atomicAdd(&cnt[bb], 1) == 7);
    __syncthreads();
    if (!lastS) return;
    __threadfence();                     // acquire: see the other 7 slices

    // ---- finisher: z = sum_ks zp[bb][ks], as hi/lo bf16 granules ----------
    // Granule (kg = node-group 0..7, h): 8 node values for column h, at
    // (kg*129 + h)*16 (129-pad spreads banks). Aliases dead staging bufs.
    unsigned char* zhi = smem[0];
    unsigned char* zlo = smem[1];
    const float* zb = zp + (size_t)bb * 65536;
#pragma unroll
    for (int i = 0; i < 4; ++i) {
        const int kg = i * 2 + (t >> 7);
        const int h  = t & 127;
        float s[8];
#pragma unroll
        for (int j = 0; j < 8; ++j) s[j] = 0.0f;
        for (int ksx = 0; ksx < 8; ++ksx) {
            const float* p = zb + ksx * 8192 + kg * 1024 + h;
#pragma unroll
            for (int j = 0; j < 8; ++j) s[j] += p[j * 128];
        }
        unsigned short hb[8];
#pragma unroll
        for (int j = 0; j < 8; ++j) hb[j] = f2bf(s[j]);
        uintx4 wh, wl;
        wh.x = (unsigned)hb[0] | ((unsigned)hb[1] << 16);
        wh.y = (unsigned)hb[2] | ((unsigned)hb[3] << 16);
        wh.z = (unsigned)hb[4] | ((unsigned)hb[5] << 16);
        wh.w = (unsigned)hb[6] | ((unsigned)hb[7] << 16);
        wl.x = pk2(s[0] - bf2f(hb[0]), s[1] - bf2f(hb[1]));
        wl.y = pk2(s[2] - bf2f(hb[2]), s[3] - bf2f(hb[3]));
        wl.z = pk2(s[4] - bf2f(hb[4]), s[5] - bf2f(hb[5]));
        wl.w = pk2(s[6] - bf2f(hb[6]), s[7] - bf2f(hb[7]));
        *(uintx4*)(zhi + (kg * 129 + h) * 16) = wh;
        *(uintx4*)(zlo + (kg * 129 + h) * 16) = wl;
    }

    // ---- M granules (hi/lo) from fp32 Mt: M[n][kg*8+j] = Mtg[(kg*8+j)*64+n]
#pragma unroll
    for (int sg = 0; sg < 2; ++sg) {
        const int g  = t * 2 + sg;
        const int kg = g >> 6, n = g & 63;
        float v[8];
#pragma unroll
        for (int j = 0; j < 8; ++j) v[j] = Mtg[(kg * 8 + j) * 64 + n];
        unsigned short hb[8];
#pragma unroll
        for (int j = 0; j < 8; ++j) hb[j] = f2bf(v[j]);
        uintx4 wh, wl;
        wh.x = (unsigned)hb[0] | ((unsigned)hb[1] << 16);
        wh.y = (unsigned)hb[2] | ((unsigned)hb[3] << 16);
        wh.z = (unsigned)hb[4] | ((unsigned)hb[5] << 16);
        wh.w = (unsigned)hb[6] | ((unsigned)hb[7] << 16);
        wl.x = pk2(v[0] - bf2f(hb[0]), v[1] - bf2f(hb[1]));
        wl.y = pk2(v[2] - bf2f(hb[2]), v[3] - bf2f(hb[3]));
        wl.z = pk2(v[4] - bf2f(hb[4]), v[5] - bf2f(hb[5]));
        wl.w = pk2(v[6] - bf2f(hb[6]), v[7] - bf2f(hb[7]));
        *(uintx4*)(mg + g * 16)        = wh;
        *(uintx4*)(mg + 8192 + g * 16) = wl;
    }
    __syncthreads();

    // ---- y_part = M @ z via error-split bf16 MFMA (K=64 -> 2 k-steps) -----
    floatx4 acc2[4][2];
#pragma unroll
    for (int nt = 0; nt < 4; ++nt)
#pragma unroll
        for (int hh = 0; hh < 2; ++hh)
            acc2[nt][hh] = (floatx4){0.f, 0.f, 0.f, 0.f};

#pragma unroll
    for (int kst = 0; kst < 2; ++kst) {
        shortx8 ah[4], al[4];
#pragma unroll
        for (int nt = 0; nt < 4; ++nt) {
            const int ga = ((kst * 4 + q) * 64 + nt * 16 + m) * 16;
            ah[nt] = *(const shortx8*)(mg + ga);
            al[nt] = *(const shortx8*)(mg + 8192 + ga);
        }
        shortx8 bh[2], bl[2];
#pragma unroll
        for (int hh = 0; hh < 2; ++hh) {
            const int gb = ((kst * 4 + q) * 129 + (wave + hh * 4) * 16 + m) * 16;
            bh[hh] = *(const shortx8*)(zhi + gb);
            bl[hh] = *(const shortx8*)(zlo + gb);
        }
#pragma unroll
        for (int nt = 0; nt < 4; ++nt)
#pragma unroll
            for (int hh = 0; hh < 2; ++hh) {
                acc2[nt][hh] = __builtin_amdgcn_mfma_f32_16x16x32_bf16(
                    ah[nt], bh[hh], acc2[nt][hh], 0, 0, 0);
                acc2[nt][hh] = __builtin_amdgcn_mfma_f32_16x16x32_bf16(
                    ah[nt], bl[hh], acc2[nt][hh], 0, 0, 0);
                acc2[nt][hh] = __builtin_amdgcn_mfma_f32_16x16x32_bf16(
                    al[nt], bh[hh], acc2[nt][hh], 0, 0, 0);
            }
    }

    // ---- y = bias + M@z (plain stores; unique owner) ----------------------
    float* yb = y + (size_t)bb * 8192;
#pragma unroll
    for (int nt = 0; nt < 4; ++nt)
#pragma unroll
        for (int hh = 0; hh < 2; ++hh) {
            const int h  = (wave + hh * 4) * 16 + m;
            const float bv = bias[h];
#pragma unroll
            for (int v = 0; v < 4; ++v) {
                const int n = nt * 16 + q * 4 + v;
                yb[n * 128 + h] = bv + acc2[nt][hh][v];
            }
        }
}

extern "C" void kernel_launch(void* const* d_in, const int* in_sizes, int n_in,
                              void* d_out, int out_size, void* d_ws, size_t ws_size,
                              hipStream_t stream) {
    const float* x    = (const float*)d_in[0];   // (2048, 2000) fp32 (flat view)
    const int*   ei   = (const int*)d_in[1];     // (2, 4096)
    const float* ew   = (const float*)d_in[2];   // (4096,)
    const float* W    = (const float*)d_in[3];   // (128, 2000) fp32
    const float* bias = (const float*)d_in[4];   // (128,)
    float* y = (float*)d_out;                    // (32, 64, 128) fp32

    float* zp = (float*)d_ws;                            // 32*8*8192 f (8 MB)
    float* Mt = zp + 2097152;                            // 4096 f
    unsigned short* wt = (unsigned short*)(Mt + 4096);   // 256*128*8 bf16 (512 KB)
    int* cnt = (int*)(wt + 262144);                      // 32 i

    prep<<<20, 512, 0, stream>>>(W, ei, ew, wt, Mt, cnt);
    gemm_fused<<<256, 256, 0, stream>>>(x, wt, Mt, bias, zp, cnt, y);
}

// Round 4
// 88.606 us; speedup vs baseline: 1.3708x; 1.3708x over previous
//
#include <hip/hip_runtime.h>
#include <hip/hip_bf16.h>

#define EPSW 1e-6f

typedef __attribute__((ext_vector_type(4))) float floatx4;
typedef __attribute__((ext_vector_type(4))) unsigned int uintx4;
typedef __attribute__((ext_vector_type(8))) short shortx8;   // 8 bf16 (4 VGPRs)

// round-to-nearest-even float -> bf16 bits (finite inputs)
__device__ __forceinline__ unsigned short f2bf(float f) {
    unsigned int u = __float_as_uint(f);
    u = (u + 0x7fffu + ((u >> 16) & 1u)) >> 16;
    return (unsigned short)u;
}

__device__ __forceinline__ unsigned int pk2(float lo, float hi) {
    return (unsigned int)f2bf(lo) | ((unsigned int)f2bf(hi) << 16);
}

__device__ __forceinline__ uintx4 pk8(floatx4 a, floatx4 b) {
    uintx4 r;
    r.x = pk2(a.x, a.y); r.y = pk2(a.z, a.w);
    r.z = pk2(b.x, b.y); r.w = pk2(b.z, b.w);
    return r;
}

// ---------------------------------------------------------------------------
// gemm_mt: 260 blocks x 512 threads (8 waves).
//   blocks 0..3  : Mt[c][n] = (A@A)[n][c], n-sliced 16 rows per block
//                  (r1-proven code; LDS aliases the staging buffers).
//   blocks 4..259: fused GEMM. g = bid-4: ks = g>>5 (K-slice of 256),
//                  bb = g&31 (batch; rows bb*64..+63).
// Both A (x, fp32) and B (W, fp32) are reg-staged with fused fp32->bf16
// convert into double-buffered LDS granule layout; 4 chunks of BK=64.
// No prep kernel, no wt workspace round-trip, no explicit s_waitcnt(0) --
// the compiler emits fine-grained vmcnt(N) as each staged register is
// consumed by the convert/pack.
// Per chunk per thread: A 32 B (granule kq,row rw) + B 64 B (granules
// (kq, rw) and (kq, rw+64)); 8-lane groups read 256 B contiguous rows.
// Compute: wave w owns h-tile w (h = w*16+m): acc[4], 8 MFMA/chunk.
// Epilogue: fp32 partials to zp[ks][row][h] (unique owner, plain stores).
// ---------------------------------------------------------------------------
__global__ __launch_bounds__(512) void gemm_mt(
        const float* __restrict__ x,
        const float* __restrict__ W,
        const int* __restrict__ ei,
        const float* __restrict__ ew,
        float* __restrict__ zp,
        float* __restrict__ Mt) {
    __shared__ __align__(16) unsigned char smem[2][24576];  // 48 KB
    const int bid = blockIdx.x;
    const int t   = threadIdx.x;

    if (bid < 4) {
        // ---- Mt = (A@A)^T build (r1-proven), n-slice [bid*16, bid*16+16) --
        float* A    = (float*)smem;            // 4096 f, A[n][k]
        float* deg  = A + 4096;
        float* dinv = deg + 64;
        if (t < 64) deg[t] = 1.0f;             // self-loop pre-added
        for (int i = t; i < 4096; i += 512) A[i] = 0.0f;
        __syncthreads();
        const int* srcp = ei;
        const int* dstp = ei + 4096;
#pragma unroll
        for (int i = 0; i < 8; ++i) {
            const int e = i * 512 + t;
            float w = ew[e];
            w = (w <= 0.0f) ? EPSW : w;
            atomicAdd(&deg[dstp[e]], w);
        }
        __syncthreads();
        if (t < 64) dinv[t] = 1.0f / sqrtf(deg[t]);
        __syncthreads();
#pragma unroll
        for (int i = 0; i < 8; ++i) {
            const int e = i * 512 + t;
            float w = ew[e];
            w = (w <= 0.0f) ? EPSW : w;
            const int s = srcp[e], d = dstp[e];
            atomicAdd(&A[d * 64 + s], dinv[s] * w * dinv[d]);
        }
        if (t < 64) atomicAdd(&A[t * 64 + t], dinv[t] * dinv[t]);
        __syncthreads();
        const int c  = t & 63;
        const int n0 = bid * 16 + (t >> 6);
        const int n1 = n0 + 8;
        float s0 = 0.0f, s1 = 0.0f;
#pragma unroll 8
        for (int k = 0; k < 64; ++k) {
            const float akc = A[k * 64 + c];
            s0 += A[n0 * 64 + k] * akc;
            s1 += A[n1 * 64 + k] * akc;
        }
        Mt[c * 64 + n0] = s0;
        Mt[c * 64 + n1] = s1;
        return;
    }

    // ---- GEMM blocks ------------------------------------------------------
    const int g     = bid - 4;
    const int ks    = g >> 5;           // 0..7
    const int bb    = g & 31;           // batch
    const int rbase = bb * 64;
    const int kbase = ks * 256;

    const int wave = t >> 6, lane = t & 63;
    const int m = lane & 15, q = lane >> 4;
    const int kq = t & 7;               // staging granule col 0..7
    const int rw = t >> 3;              // staging row 0..63

    floatx4 acc[4];
#pragma unroll
    for (int rt = 0; rt < 4; ++rt) acc[rt] = (floatx4){0.f, 0.f, 0.f, 0.f};

    floatx4 va0, va1, wb00, wb01, wb10, wb11;  // staged fp32 (A row + 2 W rows)

#define LOADC(c)                                                              \
    {                                                                         \
        const int k_ = kbase + (c) * 64 + kq * 8;                             \
        if (k_ < 2000) {                                                      \
            const float* pa_ = x + (size_t)(rbase + rw) * 2000 + k_;          \
            const float* p0_ = W + (size_t)rw * 2000 + k_;                    \
            const float* p1_ = W + (size_t)(rw + 64) * 2000 + k_;             \
            va0  = *(const floatx4*)pa_;  va1  = *(const floatx4*)(pa_ + 4);  \
            wb00 = *(const floatx4*)p0_;  wb01 = *(const floatx4*)(p0_ + 4);  \
            wb10 = *(const floatx4*)p1_;  wb11 = *(const floatx4*)(p1_ + 4);  \
        } else {                                                              \
            va0 = va1 = wb00 = wb01 = wb10 = wb11 =                           \
                (floatx4){0.f, 0.f, 0.f, 0.f};                                \
        }                                                                     \
    }

#define WRITEC(c)                                                             \
    {                                                                         \
        unsigned char* sb_ = smem[(c) & 1];                                   \
        *(uintx4*)(sb_ + kq * 1024 + rw * 16)               = pk8(va0, va1);  \
        *(uintx4*)(sb_ + 8192 + kq * 2048 + rw * 16)        = pk8(wb00, wb01);\
        *(uintx4*)(sb_ + 8192 + kq * 2048 + (rw + 64) * 16) = pk8(wb10, wb11);\
    }

    LOADC(0);
    for (int c = 0; c < 4; ++c) {
        WRITEC(c);                       // compiler waits vmcnt per register
        if (c < 3) LOADC(c + 1);         // next chunk's HBM latency overlaps
        __syncthreads();                 // all staging writes published
        const unsigned char* sb = smem[c & 1];
#pragma unroll
        for (int p = 0; p < 2; ++p) {
            const int kgq = p * 4 + q;
            shortx8 a[4];
#pragma unroll
            for (int rt = 0; rt < 4; ++rt)
                a[rt] = *(const shortx8*)(sb + kgq * 1024 + (rt * 16 + m) * 16);
            const shortx8 bf = *(const shortx8*)(sb + 8192 + kgq * 2048 +
                                                 (wave * 16 + m) * 16);
#pragma unroll
            for (int rt = 0; rt < 4; ++rt)
                acc[rt] = __builtin_amdgcn_mfma_f32_16x16x32_bf16(
                    a[rt], bf, acc[rt], 0, 0, 0);
        }
        __syncthreads();                 // reads of buf c done before reuse
    }
#undef LOADC
#undef WRITEC

    // epilogue: partial z. C/D layout: row = q*4+v, col = m.
    float* zslice = zp + ((size_t)ks * 2048 + rbase) * 128;
    const int h = wave * 16 + m;
#pragma unroll
    for (int rt = 0; rt < 4; ++rt) {
#pragma unroll
        for (int v = 0; v < 4; ++v) {
            const int n = rt * 16 + q * 4 + v;
            zslice[n * 128 + h] = acc[rt][v];
        }
    }
}

// ---------------------------------------------------------------------------
// apply_M: y[b][n][h] = bias[h] + sum_m M[n][m] * (sum_ks zp[ks][b*64+m][h])
// Grid (32 b, 8 h-chunks of 16) x 256 thr (r1-proven).
// ---------------------------------------------------------------------------
__global__ __launch_bounds__(256) void apply_M(const float* __restrict__ zp,
                                               const float* __restrict__ Mtg,
                                               const float* __restrict__ bias,
                                               float* __restrict__ y) {
    __shared__ float Ms[4096];
    __shared__ float zs[64][16];
    const int b  = blockIdx.x;
    const int hc = blockIdx.y;
    const int t  = threadIdx.x;
#pragma unroll
    for (int i = 0; i < 16; ++i) Ms[i * 256 + t] = Mtg[i * 256 + t];
#pragma unroll
    for (int i = 0; i < 4; ++i) {
        const int idx = i * 256 + t;
        const int mr = idx >> 4, hh = idx & 15;
        float s = 0.0f;
#pragma unroll
        for (int ks = 0; ks < 8; ++ks)
            s += zp[((size_t)ks * 2048 + b * 64 + mr) * 128 + hc * 16 + hh];
        zs[mr][hh] = s;
    }
    __syncthreads();
    const int h  = t & 15;
    const int n0 = (t >> 4) * 4;
    const float bv = bias[hc * 16 + h];
    float s0 = bv, s1 = bv, s2 = bv, s3 = bv;
#pragma unroll
    for (int mm = 0; mm < 64; ++mm) {
        const float zv = zs[mm][h];
        s0 += Ms[mm * 64 + n0 + 0] * zv;
        s1 += Ms[mm * 64 + n0 + 1] * zv;
        s2 += Ms[mm * 64 + n0 + 2] * zv;
        s3 += Ms[mm * 64 + n0 + 3] * zv;
    }
    float* yp = y + (size_t)b * 8192 + (size_t)n0 * 128 + hc * 16 + h;
    yp[0]   = s0;
    yp[128] = s1;
    yp[256] = s2;
    yp[384] = s3;
}

extern "C" void kernel_launch(void* const* d_in, const int* in_sizes, int n_in,
                              void* d_out, int out_size, void* d_ws, size_t ws_size,
                              hipStream_t stream) {
    const float* x    = (const float*)d_in[0];   // (2048, 2000) fp32 (flat view)
    const int*   ei   = (const int*)d_in[1];     // (2, 4096)
    const float* ew   = (const float*)d_in[2];   // (4096,)
    const float* W    = (const float*)d_in[3];   // (128, 2000) fp32
    const float* bias = (const float*)d_in[4];   // (128,)
    float* y = (float*)d_out;                    // (32, 64, 128) fp32

    float* zp = (float*)d_ws;                    // 8*2048*128 f (8 MB)
    float* Mt = zp + 2097152;                    // 4096 f

    gemm_mt<<<260, 512, 0, stream>>>(x, W, ei, ew, zp, Mt);
    apply_M<<<dim3(32, 8), 256, 0, stream>>>(zp, Mt, bias, y);
}